// Round 17
// baseline (1684.587 us; speedup 1.0000x reference)
//
#include <hip/hip_runtime.h>

#define L 128
#define NSTEPS 2
#define SCAN_B 250

typedef __attribute__((ext_vector_type(8))) short short8;
typedef __attribute__((ext_vector_type(4))) float f32x4;

static __device__ __forceinline__ unsigned short f2bf(float f) {
  unsigned int u = __float_as_uint(f);
  u += 0x7FFFu + ((u >> 16) & 1u);   // round-to-nearest-even
  return (unsigned short)(u >> 16);
}
static __device__ __forceinline__ unsigned short f2bf_trunc(float f) {
  return (unsigned short)(__float_as_uint(f) >> 16);
}
static __device__ __forceinline__ float bf2f(unsigned short h) {
  return __uint_as_float(((unsigned int)h) << 16);
}
static __device__ __forceinline__ float bfhi(unsigned u) {
  return __uint_as_float(u & 0xFFFF0000u);
}
static __device__ __forceinline__ float bflo(unsigned u) {
  return __uint_as_float(u << 16);
}
static __device__ __forceinline__ unsigned packf(float x) {
  unsigned short h = f2bf(x);
  unsigned short l = f2bf_trunc(x - bf2f(h));
  return ((unsigned)h << 16) | l;
}
static __device__ __forceinline__ float unpackf(unsigned p) {
  return bfhi(p) + bflo(p);
}

// hi16 of 8 packed u32 -> short8 (4 v_perm)
static __device__ __forceinline__ void unpack8_hi(const unsigned* __restrict__ p, short8& ah) {
  uint4 q0 = *(const uint4*)p;
  uint4 q1 = *(const uint4*)(p + 4);
  union U { unsigned u[4]; short8 s; } A;
  A.u[0] = __builtin_amdgcn_perm(q0.y, q0.x, 0x07060302u);
  A.u[1] = __builtin_amdgcn_perm(q0.w, q0.z, 0x07060302u);
  A.u[2] = __builtin_amdgcn_perm(q1.y, q1.x, 0x07060302u);
  A.u[3] = __builtin_amdgcn_perm(q1.w, q1.z, 0x07060302u);
  ah = A.s;
}

// layer-0 weights in FRAGMENT ORDER: out[s][ks][hl][fn][g][c][8]
__global__ void conv_frag_kernel(const float* __restrict__ in, unsigned short* __restrict__ out,
                                 int S) {
  int id = blockIdx.x * 256 + threadIdx.x;
  int total = S * 12 * 8192;
  if (id >= total) return;
  int chunkid = id >> 13;          // s*12 + ks
  int within = id & 8191;
  int s = chunkid / 12, ks = chunkid % 12;
  int hl = within >> 12;
  int rem = within & 4095;
  int fn = rem >> 9;
  int rem2 = rem & 511;
  int g = rem2 >> 7;
  int rem3 = rem2 & 127;
  int c = rem3 >> 3;
  int j = rem3 & 7;
  int k = ks * 32 + g * 8 + j;
  int n = fn * 16 + c;
  float x = in[(size_t)s * 512 * 128 + (size_t)k * 128 + n];
  unsigned short h = f2bf(x);
  out[id] = hl ? f2bf_trunc(x - bf2f(h)) : h;
}

// hi[s][n][k] = bf16(in[s][k][n]); lo = bf16(residual)  (layer-1 W)
__global__ void conv_split_kernel(const float* __restrict__ in,
                                  unsigned short* __restrict__ hi,
                                  unsigned short* __restrict__ lo,
                                  int Ksrc, int Kkeep, int S) {
  int id = blockIdx.x * 256 + threadIdx.x;
  int nk = 128 * Kkeep;
  int total = S * nk;
  if (id >= total) return;
  int s = id / nk;
  int rem = id - s * nk;
  int n = rem / Kkeep;
  int k = rem - n * Kkeep;
  float x = in[(size_t)s * Ksrc * 128 + (size_t)k * 128 + n];
  unsigned short h = f2bf(x);
  hi[id] = h;
  lo[id] = f2bf(x - bf2f(h));
}

// W-in-register embed: thread j holds W column j (K regs); 4 rows in flight.
template<int K>
__global__ __launch_bounds__(128, 4)
void embed_reg_kernel(const float* __restrict__ feats, const float* __restrict__ W,
                      const float* __restrict__ bias,
                      float* __restrict__ outf, unsigned* __restrict__ outp,
                      unsigned short* __restrict__ outh, int M) {
  int j = threadIdx.x;  // 128
  float w[K];
#pragma unroll
  for (int k = 0; k < K; ++k) w[k] = W[k * L + j];
  float bb = bias[j];
  int ng = (M + 3) >> 2;
  for (int gi = blockIdx.x; gi < ng; gi += gridDim.x) {
    int r0 = gi * 4;
    int r[4];
#pragma unroll
    for (int ri = 0; ri < 4; ++ri) r[ri] = min(r0 + ri, M - 1);
    float acc[4] = {bb, bb, bb, bb};
#pragma unroll
    for (int k4 = 0; k4 < K; k4 += 4) {
#pragma unroll
      for (int ri = 0; ri < 4; ++ri) {
        float4 f = *(const float4*)(feats + (size_t)r[ri] * K + k4);
        acc[ri] = fmaf(f.x, w[k4], acc[ri]);
        acc[ri] = fmaf(f.y, w[k4 + 1], acc[ri]);
        acc[ri] = fmaf(f.z, w[k4 + 2], acc[ri]);
        acc[ri] = fmaf(f.w, w[k4 + 3], acc[ri]);
      }
    }
#pragma unroll
    for (int ri = 0; ri < 4; ++ri) {
      size_t o = (size_t)r[ri] * L + j;
      if (outf) outf[o] = acc[ri];
      if (outp) outp[o] = packf(acc[ri]);
      if (outh) outh[o] = f2bf(acc[ri]);
    }
  }
}

// glob embed + step-0 bias folds + agg reset (single block, 128 threads)
__global__ void glob_embed_fold_kernel(const float* __restrict__ gin,
                                       const float* __restrict__ W, const float* __restrict__ bias,
                                       float* __restrict__ glob,
                                       const float* __restrict__ eWg, const float* __restrict__ eb0,
                                       float* __restrict__ b0e,
                                       const float* __restrict__ nWg, const float* __restrict__ nb0,
                                       float* __restrict__ b0n,
                                       float* __restrict__ node_agg, float* __restrict__ edge_agg) {
  __shared__ float gl[128];
  int j = threadIdx.x;  // 128
  float acc = bias[j];
  for (int k = 0; k < 16; ++k) acc += gin[k] * W[k * L + j];
  glob[j] = acc;
  gl[j] = acc;
  node_agg[j] = 0.f;
  edge_agg[j] = 0.f;
  __syncthreads();
  float ae = eb0[j], an = nb0[j];
  for (int k = 0; k < 128; ++k) {
    float g = gl[k];
    ae = fmaf(g, eWg[k * L + j], ae);
    an = fmaf(g, nWg[k * L + j], an);
  }
  b0e[j] = ae;
  b0n[j] = an;
}

// ---------------- CSR build ----------------
__global__ void hist_kernel(const int* __restrict__ senders, const int* __restrict__ receivers,
                            int* __restrict__ cnt1, int* __restrict__ cnt2, int E) {
  int e = blockIdx.x * 256 + threadIdx.x;
  if (e >= E) return;
  atomicAdd(&cnt1[senders[e]], 1);
  atomicAdd(&cnt2[receivers[e]], 1);
}

__global__ void scan_sum_kernel(const int* __restrict__ cnt, int* __restrict__ part,
                                int n, int chunk) {
  __shared__ int red[256];
  int b = blockIdx.x, t = threadIdx.x;
  int lo = b * chunk, hi = min(lo + chunk, n);
  red[t] = (lo + t < hi) ? cnt[lo + t] : 0;
  __syncthreads();
  for (int o = 128; o > 0; o >>= 1) { if (t < o) red[t] += red[t + o]; __syncthreads(); }
  if (t == 0) part[b] = red[0];
}

__global__ void scan_part_kernel(int* __restrict__ part, int nb) {
  if (threadIdx.x == 0) {
    int run = 0;
    for (int i = 0; i < nb; ++i) { int v = part[i]; part[i] = run; run += v; }
  }
}

__global__ void scan_write_kernel(const int* __restrict__ cnt, const int* __restrict__ part,
                                  int* __restrict__ rp, int n, int chunk, int E) {
  __shared__ int buf[256];
  int b = blockIdx.x, t = threadIdx.x;
  int lo = b * chunk, hi = min(lo + chunk, n);
  buf[t] = (lo + t < hi) ? cnt[lo + t] : 0;
  __syncthreads();
  if (t == 0) {
    int run = part[b];
    for (int i = 0; i < hi - lo; ++i) { rp[lo + i] = run; run += buf[i]; }
  }
  if (b == gridDim.x - 1 && t == 0) rp[n] = E;
}

// fill: record each edge's position in the sender-sorted and receiver-sorted layouts
__global__ void fill_kernel(const int* __restrict__ senders, const int* __restrict__ receivers,
                            const int* __restrict__ rp1, const int* __restrict__ rp2,
                            int* __restrict__ cnt1, int* __restrict__ cnt2,
                            int* __restrict__ pos1, int* __restrict__ pos2,
                            int* __restrict__ el2, int E) {
  int e = blockIdx.x * 256 + threadIdx.x;
  if (e >= E) return;
  int s = senders[e];
  int p = atomicAdd(&cnt1[s], 1);
  pos1[e] = rp1[s] + p;
  int r = receivers[e];
  int q = atomicAdd(&cnt2[r], 1);
  int w = rp2[r] + q;
  pos2[e] = w;
  el2[w] = e;            // receiver-order edge list (fallback path only)
}

// fallback: el2[w] := pos1[el2[w]]  (receiver-order -> rows of e1s)
__global__ void remap_kernel(int* __restrict__ el2, const int* __restrict__ pos1, int E) {
  int w = blockIdx.x * 256 + threadIdx.x;
  if (w >= E) return;
  el2[w] = pos1[el2[w]];
}

// sent_h/recv_h (bf16-hi) from SORTED e rows. 16 threads per node; streaming reads.
// If e2s == null, receiver side reads e1s rows via el2p indirection (fallback).
__global__ __launch_bounds__(256) void gather_kernel(
    const unsigned short* __restrict__ e1s,
    const unsigned short* __restrict__ e2s,
    const int* __restrict__ el2p,
    const int* __restrict__ rp1, const int* __restrict__ rp2,
    unsigned short* __restrict__ sent_h, unsigned short* __restrict__ recv_h, int N) {
  int t = threadIdx.x;
  int v = blockIdx.x * 16 + (t >> 4);
  if (v >= N) return;
  int cols = (t & 15) * 8;
  float a1[8], a2[8];
#pragma unroll
  for (int i = 0; i < 8; ++i) { a1[i] = 0.f; a2[i] = 0.f; }
  int s1 = rp1[v], n1 = rp1[v + 1] - s1;
  int s2 = rp2[v], n2 = rp2[v + 1] - s2;
  int mx = max(n1, n2);
  for (int j = 0; j < mx; ++j) {
    if (j < n1) {
      uint4 u = *(const uint4*)(e1s + (size_t)(s1 + j) * L + cols);
      a1[0] += bflo(u.x); a1[1] += bfhi(u.x);
      a1[2] += bflo(u.y); a1[3] += bfhi(u.y);
      a1[4] += bflo(u.z); a1[5] += bfhi(u.z);
      a1[6] += bflo(u.w); a1[7] += bfhi(u.w);
    }
    if (j < n2) {
      size_t row2 = e2s ? (size_t)(s2 + j) : (size_t)el2p[s2 + j];
      const unsigned short* src = e2s ? e2s : e1s;
      uint4 u = *(const uint4*)(src + row2 * L + cols);
      a2[0] += bflo(u.x); a2[1] += bfhi(u.x);
      a2[2] += bflo(u.y); a2[3] += bfhi(u.y);
      a2[4] += bflo(u.z); a2[5] += bfhi(u.z);
      a2[6] += bflo(u.w); a2[7] += bfhi(u.w);
    }
  }
  short8 o1, o2;
#pragma unroll
  for (int i = 0; i < 8; ++i) { o1[i] = (short)f2bf(a1[i]); o2[i] = (short)f2bf(a2[i]); }
  *(short8*)(sent_h + (size_t)v * L + cols) = o1;
  *(short8*)(recv_h + (size_t)v * L + cols) = o2;
}

#define WAITVM(n) do { __builtin_amdgcn_sched_barrier(0); \
  asm volatile("s_waitcnt vmcnt(" #n ")"); \
  __builtin_amdgcn_sched_barrier(0); } while (0)

// Fused per-step update (round-16 pipeline, depth-4 A prefetch, verified absmax 0.03125).
// EDGE epilogue scatter-writes e rows into sender-sorted e1s (and receiver-sorted e2s
// if available) so the gather becomes a streaming read.
template<bool EDGE_MODE>
__global__ __launch_bounds__(256, 3)
void block_step_kernel(const float* __restrict__ xf,
                       const unsigned* __restrict__ xp,
                       const unsigned short* __restrict__ g1h,
                       const unsigned short* __restrict__ g2h,
                       const int* __restrict__ idx1, const int* __restrict__ idx2,
                       const unsigned short* __restrict__ W0c,
                       const float* __restrict__ b0eff,
                       const unsigned short* __restrict__ W1h,
                       const unsigned short* __restrict__ W1l,
                       const float* __restrict__ b1,
                       const float* __restrict__ ln_s, const float* __restrict__ ln_b,
                       float* __restrict__ agg,
                       const int* __restrict__ pos1, const int* __restrict__ pos2,
                       unsigned short* __restrict__ e1s, unsigned short* __restrict__ e2s,
                       float* __restrict__ xf_out,
                       unsigned* __restrict__ xp_out,
                       unsigned short* __restrict__ xh_out,
                       int M) {
  __shared__ __align__(16) unsigned short SL[16384];   // 32 KB: W dbuf, later Hbf

  const int t = threadIdx.x;
  const int lane = t & 63;
  const int wg = t >> 6;          // 0..3
  const int c = lane & 15;
  const int g = lane >> 4;
  const int m0 = blockIdx.x * 128;
  const int valid = min(M - m0, 128);
  const int wbase = wg * 32;

  int rc4[2], j1[2], j2[2];
#pragma unroll
  for (int rf = 0; rf < 2; ++rf) {
    int rl = wbase + rf * 16 + c;
    int rc = min(rl, valid - 1);
    rc4[rf] = m0 + rc;
    if (EDGE_MODE) { j1[rf] = idx1[rc4[rf]]; j2[rf] = idx2[rc4[rf]]; }
    else           { j1[rf] = rc4[rf];       j2[rf] = rc4[rf]; }
  }

  const f32x4 z4 = {0.f, 0.f, 0.f, 0.f};
  f32x4 acc[2][8];
#pragma unroll
  for (int rf = 0; rf < 2; ++rf)
#pragma unroll
    for (int fn = 0; fn < 8; ++fn) acc[rf][fn] = z4;

  // ---- W staging: wave wg stages bytes [wg*4K, wg*4K+4K) of each 16KB chunk ----
  const char* wsrc = (const char*)W0c + (size_t)wg * 4096 + (size_t)lane * 16;
  char* slbase = (char*)&SL[0] + (size_t)wg * 4096;
  auto gllds_chunk = [&](int ks, int buf) {
    const char* gb = wsrc + (size_t)ks * 16384;
    char* lb = slbase + buf * 16384;
#pragma unroll
    for (int i = 0; i < 4; ++i) {
      __builtin_amdgcn_global_load_lds(
          (const __attribute__((address_space(1))) unsigned int*)(gb + i * 1024),
          (__attribute__((address_space(3))) unsigned int*)(lb + i * 1024),
          16, 0, 0);
    }
  };

  // load A-fragment (hi-only) for k-step ks (0..11): seg0 = 4 vmem, seg1/2 = 2 vmem
  auto load_frag = [&](int ks, short8* a) {
    int seg = ks >> 2, kk = ks & 3;
    if (seg == 0) {
      if (EDGE_MODE) {
#pragma unroll
        for (int rf = 0; rf < 2; ++rf) {
          const float* bp = xf + (size_t)rc4[rf] * L + g * 8 + kk * 32;
          float4 v0 = *(const float4*)bp;
          float4 v1 = *(const float4*)(bp + 4);
          a[rf][0] = (short)f2bf(v0.x); a[rf][1] = (short)f2bf(v0.y);
          a[rf][2] = (short)f2bf(v0.z); a[rf][3] = (short)f2bf(v0.w);
          a[rf][4] = (short)f2bf(v1.x); a[rf][5] = (short)f2bf(v1.y);
          a[rf][6] = (short)f2bf(v1.z); a[rf][7] = (short)f2bf(v1.w);
        }
      } else {
#pragma unroll
        for (int rf = 0; rf < 2; ++rf)
          unpack8_hi(xp + (size_t)rc4[rf] * L + g * 8 + kk * 32, a[rf]);
      }
    } else {
      const unsigned short* src = (seg == 1) ? g1h : g2h;
      const int* rsel = (seg == 1) ? j1 : j2;
#pragma unroll
      for (int rf = 0; rf < 2; ++rf)
        a[rf] = *(const short8*)(src + (size_t)rsel[rf] * L + g * 8 + kk * 32);
    }
  };

  // lane l reads byte l*16 within each (hl,fn) 1KB block -> conflict-free
  auto mfma_phase = [&](int buf, const short8* a) {
    __builtin_amdgcn_s_setprio(1);
#pragma unroll
    for (int fn = 0; fn < 8; ++fn) {
      int off = buf * 8192 + fn * 512 + g * 128 + c * 8;
      short8 bh = *(const short8*)&SL[off];
      short8 bl = *(const short8*)&SL[off + 4096];
#pragma unroll
      for (int rf = 0; rf < 2; ++rf) {
        acc[rf][fn] = __builtin_amdgcn_mfma_f32_16x16x32_bf16(a[rf], bh, acc[rf][fn], 0, 0, 0);
        acc[rf][fn] = __builtin_amdgcn_mfma_f32_16x16x32_bf16(a[rf], bl, acc[rf][fn], 0, 0, 0);
      }
    }
    __builtin_amdgcn_s_setprio(0);
  };

  // ---- layer 0: 12 k-steps; W via gllds dbuf; A 5-buffer rotation, depth 4 ----
  {
    short8 a[5][2];
    gllds_chunk(0, 0);          // 4 gllds
    load_frag(0, a[0]);         // 4 vmem (seg0)
    load_frag(1, a[1]);         // 4 vmem (seg0)
    load_frag(2, a[2]);         // 4 vmem (seg0)
    load_frag(3, a[3]);         // 4 vmem (seg0)
    WAITVM(16);                 // W(0) landed (16 frag loads may fly)
    __builtin_amdgcn_s_barrier();

#define STEP(ks, VMW)                                             \
    {                                                             \
      if ((ks) < 11) gllds_chunk((ks) + 1, ((ks) + 1) & 1);       \
      if ((ks) < 8) load_frag((ks) + 4, a[((ks) + 4) % 5]);       \
      mfma_phase((ks) & 1, a[(ks) % 5]);                          \
      if ((ks) < 11) {                                            \
        WAITVM(VMW);                                              \
        __builtin_amdgcn_s_barrier();                             \
      }                                                           \
    }
    STEP(0, 2) STEP(1, 2) STEP(2, 2) STEP(3, 2) STEP(4, 2)
    STEP(5, 2) STEP(6, 2) STEP(7, 2) STEP(8, 0) STEP(9, 0)
    STEP(10, 0) STEP(11, 0)
#undef STEP
  }
  __syncthreads();   // all waves done with W bufs before Hbf alias overwrite

  // ---- hidden: relu(acc + b0eff) -> Hbf (bf16, swizzled; wave-private stripe) ----
  unsigned short* Hbf = SL;   // aliases W dbuf (dead)
#pragma unroll
  for (int fn = 0; fn < 8; ++fn) {
    int col = fn * 16 + c;
    float bb = b0eff[col];
    int unit = col >> 3;
#pragma unroll
    for (int rf = 0; rf < 2; ++rf) {
#pragma unroll
      for (int ri = 0; ri < 4; ++ri) {
        int rl = wbase + rf * 16 + g * 4 + ri;
        float x = fmaxf(acc[rf][fn][ri] + bb, 0.f);
        Hbf[rl * 128 + ((unit ^ (rl & 15)) << 3) + (col & 7)] = f2bf(x);
      }
    }
  }
  // no barrier: each wave reads only its own 32-row stripe

  // ---- layer 1: [128 x 128] @ [128 x 128], 2-product, W1 direct L2 ----
  f32x4 acc2[2][8];
#pragma unroll
  for (int rf = 0; rf < 2; ++rf)
#pragma unroll
    for (int fn = 0; fn < 8; ++fn) acc2[rf][fn] = z4;
#pragma unroll
  for (int ks = 0; ks < 4; ++ks) {
    short8 ah[2];
#pragma unroll
    for (int rf = 0; rf < 2; ++rf) {
      int rl = wbase + rf * 16 + c;
      int unit = ks * 4 + g;
      ah[rf] = *(const short8*)&Hbf[rl * 128 + ((unit ^ (rl & 15)) << 3)];
    }
#pragma unroll
    for (int fn = 0; fn < 8; ++fn) {
      size_t wb = (size_t)(fn * 16 + c) * 128 + ks * 32 + g * 8;
      short8 bh = *(const short8*)(W1h + wb);
      short8 bl = *(const short8*)(W1l + wb);
#pragma unroll
      for (int rf = 0; rf < 2; ++rf) {
        acc2[rf][fn] = __builtin_amdgcn_mfma_f32_16x16x32_bf16(ah[rf], bh, acc2[rf][fn], 0, 0, 0);
        acc2[rf][fn] = __builtin_amdgcn_mfma_f32_16x16x32_bf16(ah[rf], bl, acc2[rf][fn], 0, 0, 0);
      }
    }
  }

  // ---- epilogue, per row-fragment ----
  float colagg[8];
#pragma unroll
  for (int fn = 0; fn < 8; ++fn) colagg[fn] = 0.f;

#pragma unroll
  for (int rf = 0; rf < 2; ++rf) {
    const int rb = wbase + rf * 16 + g * 4;
    int sp4[4], rp4[4];
    if (EDGE_MODE) {
#pragma unroll
      for (int ri = 0; ri < 4; ++ri) {
        int rc = min(rb + ri, valid - 1);
        sp4[ri] = pos1[m0 + rc];
        rp4[ri] = e2s ? pos2[m0 + rc] : 0;
      }
    }
    float sum[4] = {0.f, 0.f, 0.f, 0.f}, sq[4] = {0.f, 0.f, 0.f, 0.f};
    float xv[8][4];
#pragma unroll
    for (int fn = 0; fn < 8; ++fn) {
      int col = fn * 16 + c;
      float bb = b1[col];
#pragma unroll
      for (int ri = 0; ri < 4; ++ri) {
        int row = rb + ri;
        float e = fmaxf(acc2[rf][fn][ri] + bb, 0.f);
        if (row < valid) {
          if (EDGE_MODE) {
            unsigned short ev = f2bf(e);
            e1s[(size_t)sp4[ri] * L + col] = ev;
            if (e2s) e2s[(size_t)rp4[ri] * L + col] = ev;
          }
          colagg[fn] += e;
          float xprev;
          if (EDGE_MODE) xprev = xf[(size_t)(m0 + row) * L + col];
          else           xprev = unpackf(xp[(size_t)(m0 + row) * L + col]);
          float x = e + xprev;
          xv[fn][ri] = x;
          sum[ri] += x;
          sq[ri] += x * x;
        } else {
          xv[fn][ri] = 0.f;
        }
      }
    }
#pragma unroll
    for (int mask = 1; mask <= 8; mask <<= 1) {
#pragma unroll
      for (int ri = 0; ri < 4; ++ri) {
        sum[ri] += __shfl_xor(sum[ri], mask);
        sq[ri] += __shfl_xor(sq[ri], mask);
      }
    }
    float mu[4], rs[4];
#pragma unroll
    for (int ri = 0; ri < 4; ++ri) {
      mu[ri] = sum[ri] * (1.f / 128.f);
      float var = sq[ri] * (1.f / 128.f) - mu[ri] * mu[ri];
      rs[ri] = rsqrtf(var + 1e-6f);
    }
#pragma unroll
    for (int fn = 0; fn < 8; ++fn) {
      int col = fn * 16 + c;
      float lns = ln_s[col], lnb = ln_b[col];
#pragma unroll
      for (int ri = 0; ri < 4; ++ri) {
        int row = rb + ri;
        if (row < valid) {
          float y = (xv[fn][ri] - mu[ri]) * rs[ri] * lns + lnb;
          if (xf_out) xf_out[(size_t)(m0 + row) * L + col] = y;
          if (xp_out) xp_out[(size_t)(m0 + row) * L + col] = packf(y);
          if (xh_out) xh_out[(size_t)(m0 + row) * L + col] = f2bf(y);
        }
      }
    }
  }

  // column aggregate
#pragma unroll
  for (int mask = 16; mask <= 32; mask <<= 1)
#pragma unroll
    for (int fn = 0; fn < 8; ++fn) colagg[fn] += __shfl_xor(colagg[fn], mask);
  __syncthreads();               // all Hbf reads complete; reuse as float scratch
  float* F = (float*)SL;
  if (lane < 16) {
#pragma unroll
    for (int fn = 0; fn < 8; ++fn) F[wg * 128 + fn * 16 + lane] = colagg[fn];
  }
  __syncthreads();
  if (t < 128) {
    float s = 0.f;
#pragma unroll
    for (int w = 0; w < 4; ++w) s += F[w * 128 + t];
    atomicAdd(agg + t, s);
  }
}

// global update + LN + (optionally) next step's bias folds + agg reset
__global__ void glob_step_kernel(float* __restrict__ glob,
                                 float* __restrict__ node_agg, float* __restrict__ edge_agg,
                                 const float* __restrict__ W0, const float* __restrict__ b0,
                                 const float* __restrict__ W1, const float* __restrict__ b1,
                                 const float* __restrict__ ln_s, const float* __restrict__ ln_b,
                                 const float* __restrict__ eWg, const float* __restrict__ eb0,
                                 float* __restrict__ b0e,
                                 const float* __restrict__ nWg, const float* __restrict__ nb0,
                                 float* __restrict__ b0n) {
  __shared__ float gin[384];
  __shared__ float h[128];
  __shared__ float red4[4];
  __shared__ float gl[128];
  int j = threadIdx.x;  // 128
  gin[j] = node_agg[j];
  gin[128 + j] = edge_agg[j];
  gin[256 + j] = glob[j];
  __syncthreads();
  node_agg[j] = 0.f;
  edge_agg[j] = 0.f;
  float a = b0[j];
  for (int k = 0; k < 384; ++k) a += gin[k] * W0[k * L + j];
  h[j] = fmaxf(a, 0.f);
  __syncthreads();
  float o = b1[j];
  for (int k = 0; k < 128; ++k) o += h[k] * W1[k * L + j];
  o = fmaxf(o, 0.f);
  float x = o + gin[256 + j];
  float sum = x, sq = x * x;
  for (int m = 1; m < 64; m <<= 1) { sum += __shfl_xor(sum, m); sq += __shfl_xor(sq, m); }
  if ((j & 63) == 0) { red4[(j >> 6) * 2] = sum; red4[(j >> 6) * 2 + 1] = sq; }
  __syncthreads();
  sum = red4[0] + red4[2]; sq = red4[1] + red4[3];
  float mu = sum * (1.f / 128.f);
  float var = sq * (1.f / 128.f) - mu * mu;
  float rsd = rsqrtf(var + 1e-6f);
  float gnew = (x - mu) * rsd * ln_s[j] + ln_b[j];
  glob[j] = gnew;
  gl[j] = gnew;
  __syncthreads();
  if (eWg) {
    float ae = eb0[j], an = nb0[j];
    for (int k = 0; k < 128; ++k) {
      float g = gl[k];
      ae = fmaf(g, eWg[k * L + j], ae);
      an = fmaf(g, nWg[k * L + j], an);
    }
    b0e[j] = ae;
    b0n[j] = an;
  }
}

__global__ void decode_kernel(const float* __restrict__ glob, const float* __restrict__ W,
                              const float* __restrict__ bias, float* __restrict__ out) {
  int j = threadIdx.x;  // 128
  float a = bias[j];
  for (int k = 0; k < 128; ++k) a += glob[k] * W[k * L + j];
  out[j] = a;
}

extern "C" void kernel_launch(void* const* d_in, const int* in_sizes, int n_in,
                              void* d_out, int out_size, void* d_ws, size_t ws_size,
                              hipStream_t stream) {
  const float* node_feats = (const float*)d_in[0];
  const float* edge_feats = (const float*)d_in[1];
  const float* globals_   = (const float*)d_in[2];
  const int*   senders    = (const int*)d_in[3];
  const int*   receivers  = (const int*)d_in[4];
  const float* emb_node_W = (const float*)d_in[5];
  const float* emb_node_b = (const float*)d_in[6];
  const float* emb_edge_W = (const float*)d_in[7];
  const float* emb_edge_b = (const float*)d_in[8];
  const float* emb_glob_W = (const float*)d_in[9];
  const float* emb_glob_b = (const float*)d_in[10];
  const float* edge_W0 = (const float*)d_in[11];
  const float* edge_b0 = (const float*)d_in[12];
  const float* edge_W1 = (const float*)d_in[13];
  const float* edge_b1 = (const float*)d_in[14];
  const float* node_W0 = (const float*)d_in[15];
  const float* node_b0 = (const float*)d_in[16];
  const float* node_W1 = (const float*)d_in[17];
  const float* node_b1 = (const float*)d_in[18];
  const float* glob_W0 = (const float*)d_in[19];
  const float* glob_b0 = (const float*)d_in[20];
  const float* glob_W1 = (const float*)d_in[21];
  const float* glob_b1 = (const float*)d_in[22];
  const float* ln_node_s = (const float*)d_in[23];
  const float* ln_node_b = (const float*)d_in[24];
  const float* ln_edge_s = (const float*)d_in[25];
  const float* ln_edge_b = (const float*)d_in[26];
  const float* ln_glob_s = (const float*)d_in[27];
  const float* ln_glob_b = (const float*)d_in[28];
  const float* dec_W = (const float*)d_in[29];
  const float* dec_b = (const float*)d_in[30];

  const int N = in_sizes[0] / 64;
  const int E = in_sizes[1] / 32;

  float* nodes = (float*)d_out;                   // [N][128]
  float* edges = nodes + (size_t)N * L;           // [E][128] (live fp32 edge state)
  float* gout  = edges + (size_t)E * L;           // [128]

  char* wp = (char*)d_ws;
  auto alloc = [&](size_t bytes) -> char* {
    char* p = wp;
    wp += (bytes + 255) & ~(size_t)255;
    return p;
  };
  float* glob = (float*)alloc(512);
  float* node_agg = (float*)alloc(512);
  float* edge_agg = (float*)alloc(512);
  float* b0e_eff = (float*)alloc(512);
  float* b0n_eff = (float*)alloc(512);
  unsigned short* eW0c = (unsigned short*)alloc((size_t)NSTEPS * 12 * 8192 * 2);
  unsigned short* nW0c = (unsigned short*)alloc((size_t)NSTEPS * 12 * 8192 * 2);
  unsigned short* eW1h = (unsigned short*)alloc((size_t)NSTEPS * 128 * 128 * 2);
  unsigned short* eW1l = (unsigned short*)alloc((size_t)NSTEPS * 128 * 128 * 2);
  unsigned short* nW1h = (unsigned short*)alloc((size_t)NSTEPS * 128 * 128 * 2);
  unsigned short* nW1l = (unsigned short*)alloc((size_t)NSTEPS * 128 * 128 * 2);
  unsigned* nodes_p = (unsigned*)alloc((size_t)N * L * 4);
  unsigned short* nodes_h = (unsigned short*)alloc((size_t)N * L * 2);
  unsigned short* sent_h  = (unsigned short*)alloc((size_t)N * L * 2);
  unsigned short* recv_h  = (unsigned short*)alloc((size_t)N * L * 2);
  int* rp1 = (int*)alloc((size_t)(N + 1) * 4);
  int* rp2 = (int*)alloc((size_t)(N + 1) * 4);
  int* cnt1 = (int*)alloc((size_t)N * 4);
  int* cnt2 = (int*)alloc((size_t)N * 4);
  int* pos1 = (int*)alloc((size_t)E * 4);
  int* pos2 = (int*)alloc((size_t)E * 4);
  int* el2 = (int*)alloc((size_t)E * 4);
  int* part = (int*)alloc(SCAN_B * 4);
  unsigned short* e1s = (unsigned short*)alloc((size_t)E * L * 2);
  size_t need_base = (size_t)(wp - (char*)d_ws);
  unsigned short* e2s = (unsigned short*)alloc((size_t)E * L * 2);
  size_t need_full = (size_t)(wp - (char*)d_ws);
  const bool two = (ws_size >= need_full);
  (void)need_base;
  unsigned short* e2s_use = two ? e2s : nullptr;

  // weight prep: layer0 fragment-ordered (conflict-free), layer1 transposed hi/lo
  conv_frag_kernel<<<(NSTEPS * 12 * 8192 + 255) / 256, 256, 0, stream>>>(edge_W0, eW0c, NSTEPS);
  conv_frag_kernel<<<(NSTEPS * 12 * 8192 + 255) / 256, 256, 0, stream>>>(node_W0, nW0c, NSTEPS);
  conv_split_kernel<<<(NSTEPS * 128 * 128 + 255) / 256, 256, 0, stream>>>(edge_W1, eW1h, eW1l, 128, 128, NSTEPS);
  conv_split_kernel<<<(NSTEPS * 128 * 128 + 255) / 256, 256, 0, stream>>>(node_W1, nW1h, nW1l, 128, 128, NSTEPS);

  // embeddings (exact fp32 math, W-in-register)
  embed_reg_kernel<64><<<2048, 128, 0, stream>>>(node_feats, emb_node_W, emb_node_b,
                                                 nullptr, nodes_p, nodes_h, N);
  embed_reg_kernel<32><<<4096, 128, 0, stream>>>(edge_feats, emb_edge_W, emb_edge_b,
                                                 edges, nullptr, nullptr, E);
  glob_embed_fold_kernel<<<1, 128, 0, stream>>>(globals_, emb_glob_W, emb_glob_b, glob,
                                                edge_W0 + 384 * L, edge_b0, b0e_eff,
                                                node_W0 + 384 * L, node_b0, b0n_eff,
                                                node_agg, edge_agg);

  // CSR build (once per launch)
  const int chunk = (N + SCAN_B - 1) / SCAN_B;
  hipMemsetAsync(cnt1, 0, (size_t)N * 4, stream);
  hipMemsetAsync(cnt2, 0, (size_t)N * 4, stream);
  hist_kernel<<<(E + 255) / 256, 256, 0, stream>>>(senders, receivers, cnt1, cnt2, E);
  scan_sum_kernel<<<SCAN_B, 256, 0, stream>>>(cnt1, part, N, chunk);
  scan_part_kernel<<<1, 64, 0, stream>>>(part, SCAN_B);
  scan_write_kernel<<<SCAN_B, 256, 0, stream>>>(cnt1, part, rp1, N, chunk, E);
  scan_sum_kernel<<<SCAN_B, 256, 0, stream>>>(cnt2, part, N, chunk);
  scan_part_kernel<<<1, 64, 0, stream>>>(part, SCAN_B);
  scan_write_kernel<<<SCAN_B, 256, 0, stream>>>(cnt2, part, rp2, N, chunk, E);
  hipMemsetAsync(cnt1, 0, (size_t)N * 4, stream);
  hipMemsetAsync(cnt2, 0, (size_t)N * 4, stream);
  fill_kernel<<<(E + 255) / 256, 256, 0, stream>>>(senders, receivers, rp1, rp2, cnt1, cnt2,
                                                   pos1, pos2, el2, E);
  if (!two)
    remap_kernel<<<(E + 255) / 256, 256, 0, stream>>>(el2, pos1, E);

  const int egrid = (E + 127) / 128;
  const int ngrid = (N + 127) / 128;

  for (int s = 0; s < NSTEPS; ++s) {
    const bool last = (s == NSTEPS - 1);

    block_step_kernel<true><<<egrid, 256, 0, stream>>>(
        edges, nullptr, nodes_h, nodes_h, senders, receivers,
        eW0c + (size_t)s * 12 * 8192, b0e_eff,
        eW1h + (size_t)s * 128 * 128, eW1l + (size_t)s * 128 * 128, edge_b1 + s * L,
        ln_edge_s + s * L, ln_edge_b + s * L,
        edge_agg, pos1, pos2, e1s, e2s_use, edges, nullptr, nullptr, E);

    gather_kernel<<<(N + 15) / 16, 256, 0, stream>>>(e1s, e2s_use, el2, rp1, rp2,
                                                     sent_h, recv_h, N);

    block_step_kernel<false><<<ngrid, 256, 0, stream>>>(
        nullptr, nodes_p, sent_h, recv_h, nullptr, nullptr,
        nW0c + (size_t)s * 12 * 8192, b0n_eff,
        nW1h + (size_t)s * 128 * 128, nW1l + (size_t)s * 128 * 128, node_b1 + s * L,
        ln_node_s + s * L, ln_node_b + s * L,
        node_agg, nullptr, nullptr, nullptr, nullptr,
        last ? nodes : nullptr, last ? nullptr : nodes_p,
        last ? nullptr : nodes_h, N);

    glob_step_kernel<<<1, 128, 0, stream>>>(
        glob, node_agg, edge_agg,
        glob_W0 + (size_t)s * 384 * L, glob_b0 + s * L,
        glob_W1 + (size_t)s * 128 * L, glob_b1 + s * L,
        ln_glob_s + s * L, ln_glob_b + s * L,
        last ? nullptr : (edge_W0 + (size_t)1 * 512 * L + 384 * L),
        last ? nullptr : (edge_b0 + 1 * L), b0e_eff,
        last ? nullptr : (node_W0 + (size_t)1 * 512 * L + 384 * L),
        last ? nullptr : (node_b0 + 1 * L), b0n_eff);
  }

  decode_kernel<<<1, 128, 0, stream>>>(glob, dec_W, dec_b, gout);
}

// Round 18
// 1556.538 us; speedup vs baseline: 1.0823x; 1.0823x over previous
//
#include <hip/hip_runtime.h>

#define L 128
#define NSTEPS 2
#define SCAN_B 250

typedef __attribute__((ext_vector_type(8))) short short8;
typedef __attribute__((ext_vector_type(4))) float f32x4;

static __device__ __forceinline__ unsigned short f2bf(float f) {
  unsigned int u = __float_as_uint(f);
  u += 0x7FFFu + ((u >> 16) & 1u);   // round-to-nearest-even
  return (unsigned short)(u >> 16);
}
static __device__ __forceinline__ unsigned short f2bf_trunc(float f) {
  return (unsigned short)(__float_as_uint(f) >> 16);
}
static __device__ __forceinline__ float bf2f(unsigned short h) {
  return __uint_as_float(((unsigned int)h) << 16);
}
static __device__ __forceinline__ float bfhi(unsigned u) {
  return __uint_as_float(u & 0xFFFF0000u);
}
static __device__ __forceinline__ float bflo(unsigned u) {
  return __uint_as_float(u << 16);
}
static __device__ __forceinline__ unsigned packf(float x) {
  unsigned short h = f2bf(x);
  unsigned short l = f2bf_trunc(x - bf2f(h));
  return ((unsigned)h << 16) | l;
}
static __device__ __forceinline__ float unpackf(unsigned p) {
  return bfhi(p) + bflo(p);
}

// hi16 of 8 packed u32 -> short8 (4 v_perm)
static __device__ __forceinline__ void unpack8_hi(const unsigned* __restrict__ p, short8& ah) {
  uint4 q0 = *(const uint4*)p;
  uint4 q1 = *(const uint4*)(p + 4);
  union U { unsigned u[4]; short8 s; } A;
  A.u[0] = __builtin_amdgcn_perm(q0.y, q0.x, 0x07060302u);
  A.u[1] = __builtin_amdgcn_perm(q0.w, q0.z, 0x07060302u);
  A.u[2] = __builtin_amdgcn_perm(q1.y, q1.x, 0x07060302u);
  A.u[3] = __builtin_amdgcn_perm(q1.w, q1.z, 0x07060302u);
  ah = A.s;
}

// layer-0 weights in FRAGMENT ORDER: out[s][ks][hl][fn][g][c][8]
// k = ks*32 + g*8 + j (first 384 rows only), n = fn*16 + c; hl: 0=hi 1=lo
// lane l = g*16+c reads byte l*16 within each (hl,fn) block -> conflict-free.
__global__ void conv_frag_kernel(const float* __restrict__ in, unsigned short* __restrict__ out,
                                 int S) {
  int id = blockIdx.x * 256 + threadIdx.x;
  int total = S * 12 * 8192;
  if (id >= total) return;
  int chunkid = id >> 13;          // s*12 + ks
  int within = id & 8191;
  int s = chunkid / 12, ks = chunkid % 12;
  int hl = within >> 12;
  int rem = within & 4095;
  int fn = rem >> 9;
  int rem2 = rem & 511;
  int g = rem2 >> 7;
  int rem3 = rem2 & 127;
  int c = rem3 >> 3;
  int j = rem3 & 7;
  int k = ks * 32 + g * 8 + j;
  int n = fn * 16 + c;
  float x = in[(size_t)s * 512 * 128 + (size_t)k * 128 + n];
  unsigned short h = f2bf(x);
  out[id] = hl ? f2bf_trunc(x - bf2f(h)) : h;
}

// hi[s][n][k] = bf16(in[s][k][n]) for k < Kkeep; lo = bf16(residual)  (layer-1 W)
__global__ void conv_split_kernel(const float* __restrict__ in,
                                  unsigned short* __restrict__ hi,
                                  unsigned short* __restrict__ lo,
                                  int Ksrc, int Kkeep, int S) {
  int id = blockIdx.x * 256 + threadIdx.x;
  int nk = 128 * Kkeep;
  int total = S * nk;
  if (id >= total) return;
  int s = id / nk;
  int rem = id - s * nk;
  int n = rem / Kkeep;
  int k = rem - n * Kkeep;
  float x = in[(size_t)s * Ksrc * 128 + (size_t)k * 128 + n];
  unsigned short h = f2bf(x);
  hi[id] = h;
  lo[id] = f2bf(x - bf2f(h));
}

// W-in-register embed: thread j holds W column j (K regs); 4 rows in flight.
template<int K>
__global__ __launch_bounds__(128, 4)
void embed_reg_kernel(const float* __restrict__ feats, const float* __restrict__ W,
                      const float* __restrict__ bias,
                      float* __restrict__ outf, unsigned* __restrict__ outp,
                      unsigned short* __restrict__ outh, int M) {
  int j = threadIdx.x;  // 128
  float w[K];
#pragma unroll
  for (int k = 0; k < K; ++k) w[k] = W[k * L + j];
  float bb = bias[j];
  int ng = (M + 3) >> 2;
  for (int gi = blockIdx.x; gi < ng; gi += gridDim.x) {
    int r0 = gi * 4;
    int r[4];
#pragma unroll
    for (int ri = 0; ri < 4; ++ri) r[ri] = min(r0 + ri, M - 1);
    float acc[4] = {bb, bb, bb, bb};
#pragma unroll
    for (int k4 = 0; k4 < K; k4 += 4) {
#pragma unroll
      for (int ri = 0; ri < 4; ++ri) {
        float4 f = *(const float4*)(feats + (size_t)r[ri] * K + k4);
        acc[ri] = fmaf(f.x, w[k4], acc[ri]);
        acc[ri] = fmaf(f.y, w[k4 + 1], acc[ri]);
        acc[ri] = fmaf(f.z, w[k4 + 2], acc[ri]);
        acc[ri] = fmaf(f.w, w[k4 + 3], acc[ri]);
      }
    }
#pragma unroll
    for (int ri = 0; ri < 4; ++ri) {
      size_t o = (size_t)r[ri] * L + j;
      if (outf) outf[o] = acc[ri];
      if (outp) outp[o] = packf(acc[ri]);
      if (outh) outh[o] = f2bf(acc[ri]);
    }
  }
}

// glob embed + step-0 bias folds + agg reset (single block, 128 threads)
__global__ void glob_embed_fold_kernel(const float* __restrict__ gin,
                                       const float* __restrict__ W, const float* __restrict__ bias,
                                       float* __restrict__ glob,
                                       const float* __restrict__ eWg, const float* __restrict__ eb0,
                                       float* __restrict__ b0e,
                                       const float* __restrict__ nWg, const float* __restrict__ nb0,
                                       float* __restrict__ b0n,
                                       float* __restrict__ node_agg, float* __restrict__ edge_agg) {
  __shared__ float gl[128];
  int j = threadIdx.x;  // 128
  float acc = bias[j];
  for (int k = 0; k < 16; ++k) acc += gin[k] * W[k * L + j];
  glob[j] = acc;
  gl[j] = acc;
  node_agg[j] = 0.f;
  edge_agg[j] = 0.f;
  __syncthreads();
  float ae = eb0[j], an = nb0[j];
  for (int k = 0; k < 128; ++k) {
    float g = gl[k];
    ae = fmaf(g, eWg[k * L + j], ae);
    an = fmaf(g, nWg[k * L + j], an);
  }
  b0e[j] = ae;
  b0n[j] = an;
}

// ---------------- CSR build ----------------
__global__ void hist_kernel(const int* __restrict__ senders, const int* __restrict__ receivers,
                            int* __restrict__ cnt1, int* __restrict__ cnt2, int E) {
  int e = blockIdx.x * 256 + threadIdx.x;
  if (e >= E) return;
  atomicAdd(&cnt1[senders[e]], 1);
  atomicAdd(&cnt2[receivers[e]], 1);
}

__global__ void scan_sum_kernel(const int* __restrict__ cnt, int* __restrict__ part,
                                int n, int chunk) {
  __shared__ int red[256];
  int b = blockIdx.x, t = threadIdx.x;
  int lo = b * chunk, hi = min(lo + chunk, n);
  red[t] = (lo + t < hi) ? cnt[lo + t] : 0;
  __syncthreads();
  for (int o = 128; o > 0; o >>= 1) { if (t < o) red[t] += red[t + o]; __syncthreads(); }
  if (t == 0) part[b] = red[0];
}

__global__ void scan_part_kernel(int* __restrict__ part, int nb) {
  if (threadIdx.x == 0) {
    int run = 0;
    for (int i = 0; i < nb; ++i) { int v = part[i]; part[i] = run; run += v; }
  }
}

__global__ void scan_write_kernel(const int* __restrict__ cnt, const int* __restrict__ part,
                                  int* __restrict__ rp, int n, int chunk, int E) {
  __shared__ int buf[256];
  int b = blockIdx.x, t = threadIdx.x;
  int lo = b * chunk, hi = min(lo + chunk, n);
  buf[t] = (lo + t < hi) ? cnt[lo + t] : 0;
  __syncthreads();
  if (t == 0) {
    int run = part[b];
    for (int i = 0; i < hi - lo; ++i) { rp[lo + i] = run; run += buf[i]; }
  }
  if (b == gridDim.x - 1 && t == 0) rp[n] = E;
}

__global__ void fill_kernel(const int* __restrict__ senders, const int* __restrict__ receivers,
                            const int* __restrict__ rp1, const int* __restrict__ rp2,
                            int* __restrict__ cnt1, int* __restrict__ cnt2,
                            int* __restrict__ el1, int* __restrict__ el2, int E) {
  int e = blockIdx.x * 256 + threadIdx.x;
  if (e >= E) return;
  int s = senders[e];
  int p = atomicAdd(&cnt1[s], 1);
  el1[rp1[s] + p] = e;
  int r = receivers[e];
  int q = atomicAdd(&cnt2[r], 1);
  el2[rp2[r] + q] = e;
}

// sent_h/recv_h (bf16-hi) from bf16 e-buffer via CSR. 16 threads per node.
__global__ __launch_bounds__(256) void gather_kernel(
    const unsigned short* __restrict__ e16,
    const int* __restrict__ rp1, const int* __restrict__ el1,
    const int* __restrict__ rp2, const int* __restrict__ el2,
    unsigned short* __restrict__ sent_h, unsigned short* __restrict__ recv_h, int N) {
  int t = threadIdx.x;
  int v = blockIdx.x * 16 + (t >> 4);
  if (v >= N) return;
  int cols = (t & 15) * 8;
  float a1[8], a2[8];
#pragma unroll
  for (int i = 0; i < 8; ++i) { a1[i] = 0.f; a2[i] = 0.f; }
  int s1 = rp1[v], n1 = rp1[v + 1] - s1;
  int s2 = rp2[v], n2 = rp2[v + 1] - s2;
  int mx = max(n1, n2);
  for (int j = 0; j < mx; ++j) {
    if (j < n1) {
      uint4 u = *(const uint4*)(e16 + (size_t)el1[s1 + j] * L + cols);
      a1[0] += bflo(u.x); a1[1] += bfhi(u.x);
      a1[2] += bflo(u.y); a1[3] += bfhi(u.y);
      a1[4] += bflo(u.z); a1[5] += bfhi(u.z);
      a1[6] += bflo(u.w); a1[7] += bfhi(u.w);
    }
    if (j < n2) {
      uint4 u = *(const uint4*)(e16 + (size_t)el2[s2 + j] * L + cols);
      a2[0] += bflo(u.x); a2[1] += bfhi(u.x);
      a2[2] += bflo(u.y); a2[3] += bfhi(u.y);
      a2[4] += bflo(u.z); a2[5] += bfhi(u.z);
      a2[6] += bflo(u.w); a2[7] += bfhi(u.w);
    }
  }
  short8 o1, o2;
#pragma unroll
  for (int i = 0; i < 8; ++i) { o1[i] = (short)f2bf(a1[i]); o2[i] = (short)f2bf(a2[i]); }
  *(short8*)(sent_h + (size_t)v * L + cols) = o1;
  *(short8*)(recv_h + (size_t)v * L + cols) = o2;
}

#define WAITVM(n) do { __builtin_amdgcn_sched_barrier(0); \
  asm volatile("s_waitcnt vmcnt(" #n ")"); \
  __builtin_amdgcn_sched_barrier(0); } while (0)

// Fused per-step update. 256 threads = 4 waves; each wave owns 32 rows x 128 cols
// (acc[2][8]=64 AGPR; A prefetch depth 4, 5-buffer rotation -> ~96 VGPR, still
// 3 waves/SIMD). Layer-0 W via global_load_lds into 2x16KB LDS dbuf; counted-vmcnt
// raw-barrier pipeline. A-operands bf16-hi, 2-product MFMA (Ah*Bh + Ah*Bl).
// Hidden bf16 tile aliases W dbuf. Verified absmax 0.03125 (race-free schedule).
template<bool EDGE_MODE>
__global__ __launch_bounds__(256, 3)
void block_step_kernel(const float* __restrict__ xf,          // EDGE: fp32 self state
                       const unsigned* __restrict__ xp,       // NODE: packed self state
                       const unsigned short* __restrict__ g1h, // nodes_h | sent_h
                       const unsigned short* __restrict__ g2h, // nodes_h | recv_h
                       const int* __restrict__ idx1, const int* __restrict__ idx2,
                       const unsigned short* __restrict__ W0c, // [12][2][8][4][16][8] frag order
                       const float* __restrict__ b0eff,
                       const unsigned short* __restrict__ W1h,
                       const unsigned short* __restrict__ W1l,
                       const float* __restrict__ b1,
                       const float* __restrict__ ln_s, const float* __restrict__ ln_b,
                       float* __restrict__ agg,
                       unsigned short* __restrict__ e_out,
                       float* __restrict__ xf_out,
                       unsigned* __restrict__ xp_out,
                       unsigned short* __restrict__ xh_out,
                       int M) {
  __shared__ __align__(16) unsigned short SL[16384];   // 32 KB: W dbuf, later Hbf

  const int t = threadIdx.x;
  const int lane = t & 63;
  const int wg = t >> 6;          // 0..3
  const int c = lane & 15;
  const int g = lane >> 4;
  const int m0 = blockIdx.x * 128;
  const int valid = min(M - m0, 128);
  const int wbase = wg * 32;

  int rc4[2], j1[2], j2[2];
#pragma unroll
  for (int rf = 0; rf < 2; ++rf) {
    int rl = wbase + rf * 16 + c;
    int rc = min(rl, valid - 1);
    rc4[rf] = m0 + rc;
    if (EDGE_MODE) { j1[rf] = idx1[rc4[rf]]; j2[rf] = idx2[rc4[rf]]; }
    else           { j1[rf] = rc4[rf];       j2[rf] = rc4[rf]; }
  }

  const f32x4 z4 = {0.f, 0.f, 0.f, 0.f};
  f32x4 acc[2][8];
#pragma unroll
  for (int rf = 0; rf < 2; ++rf)
#pragma unroll
    for (int fn = 0; fn < 8; ++fn) acc[rf][fn] = z4;

  // ---- W staging: wave wg stages bytes [wg*4K, wg*4K+4K) of each 16KB chunk ----
  const char* wsrc = (const char*)W0c + (size_t)wg * 4096 + (size_t)lane * 16;
  char* slbase = (char*)&SL[0] + (size_t)wg * 4096;
  auto gllds_chunk = [&](int ks, int buf) {
    const char* gb = wsrc + (size_t)ks * 16384;
    char* lb = slbase + buf * 16384;
#pragma unroll
    for (int i = 0; i < 4; ++i) {
      __builtin_amdgcn_global_load_lds(
          (const __attribute__((address_space(1))) unsigned int*)(gb + i * 1024),
          (__attribute__((address_space(3))) unsigned int*)(lb + i * 1024),
          16, 0, 0);
    }
  };

  // load A-fragment (hi-only) for k-step ks (0..11): seg0 = 4 vmem, seg1/2 = 2 vmem
  auto load_frag = [&](int ks, short8* a) {
    int seg = ks >> 2, kk = ks & 3;
    if (seg == 0) {
      if (EDGE_MODE) {
#pragma unroll
        for (int rf = 0; rf < 2; ++rf) {
          const float* bp = xf + (size_t)rc4[rf] * L + g * 8 + kk * 32;
          float4 v0 = *(const float4*)bp;
          float4 v1 = *(const float4*)(bp + 4);
          a[rf][0] = (short)f2bf(v0.x); a[rf][1] = (short)f2bf(v0.y);
          a[rf][2] = (short)f2bf(v0.z); a[rf][3] = (short)f2bf(v0.w);
          a[rf][4] = (short)f2bf(v1.x); a[rf][5] = (short)f2bf(v1.y);
          a[rf][6] = (short)f2bf(v1.z); a[rf][7] = (short)f2bf(v1.w);
        }
      } else {
#pragma unroll
        for (int rf = 0; rf < 2; ++rf)
          unpack8_hi(xp + (size_t)rc4[rf] * L + g * 8 + kk * 32, a[rf]);
      }
    } else {
      const unsigned short* src = (seg == 1) ? g1h : g2h;
      const int* rsel = (seg == 1) ? j1 : j2;
#pragma unroll
      for (int rf = 0; rf < 2; ++rf)
        a[rf] = *(const short8*)(src + (size_t)rsel[rf] * L + g * 8 + kk * 32);
    }
  };

  // lane l reads byte l*16 within each (hl,fn) 1KB block -> conflict-free
  auto mfma_phase = [&](int buf, const short8* a) {
    __builtin_amdgcn_s_setprio(1);
#pragma unroll
    for (int fn = 0; fn < 8; ++fn) {
      int off = buf * 8192 + fn * 512 + g * 128 + c * 8;
      short8 bh = *(const short8*)&SL[off];
      short8 bl = *(const short8*)&SL[off + 4096];
#pragma unroll
      for (int rf = 0; rf < 2; ++rf) {
        acc[rf][fn] = __builtin_amdgcn_mfma_f32_16x16x32_bf16(a[rf], bh, acc[rf][fn], 0, 0, 0);
        acc[rf][fn] = __builtin_amdgcn_mfma_f32_16x16x32_bf16(a[rf], bl, acc[rf][fn], 0, 0, 0);
      }
    }
    __builtin_amdgcn_s_setprio(0);
  };

  // ---- layer 0: 12 k-steps; W via gllds dbuf; A 5-buffer rotation, depth 4 ----
  {
    short8 a[5][2];
    gllds_chunk(0, 0);          // 4 gllds
    load_frag(0, a[0]);         // 4 vmem (seg0)
    load_frag(1, a[1]);         // 4 vmem (seg0)
    load_frag(2, a[2]);         // 4 vmem (seg0)
    load_frag(3, a[3]);         // 4 vmem (seg0)
    WAITVM(16);                 // W(0) landed (16 frag loads may fly)
    __builtin_amdgcn_s_barrier();

#define STEP(ks, VMW)                                             \
    {                                                             \
      if ((ks) < 11) gllds_chunk((ks) + 1, ((ks) + 1) & 1);       \
      if ((ks) < 8) load_frag((ks) + 4, a[((ks) + 4) % 5]);       \
      mfma_phase((ks) & 1, a[(ks) % 5]);                          \
      if ((ks) < 11) {                                            \
        WAITVM(VMW);                                              \
        __builtin_amdgcn_s_barrier();                             \
      }                                                           \
    }
    STEP(0, 2) STEP(1, 2) STEP(2, 2) STEP(3, 2) STEP(4, 2)
    STEP(5, 2) STEP(6, 2) STEP(7, 2) STEP(8, 0) STEP(9, 0)
    STEP(10, 0) STEP(11, 0)
#undef STEP
  }
  __syncthreads();   // all waves done with W bufs before Hbf alias overwrite

  // ---- hidden: relu(acc + b0eff) -> Hbf (bf16, swizzled; wave-private stripe) ----
  unsigned short* Hbf = SL;   // aliases W dbuf (dead)
#pragma unroll
  for (int fn = 0; fn < 8; ++fn) {
    int col = fn * 16 + c;
    float bb = b0eff[col];
    int unit = col >> 3;
#pragma unroll
    for (int rf = 0; rf < 2; ++rf) {
#pragma unroll
      for (int ri = 0; ri < 4; ++ri) {
        int rl = wbase + rf * 16 + g * 4 + ri;
        float x = fmaxf(acc[rf][fn][ri] + bb, 0.f);
        Hbf[rl * 128 + ((unit ^ (rl & 15)) << 3) + (col & 7)] = f2bf(x);
      }
    }
  }
  // no barrier: each wave reads only its own 32-row stripe

  // ---- layer 1: [128 x 128] @ [128 x 128], 2-product, W1 direct L2 ----
  f32x4 acc2[2][8];
#pragma unroll
  for (int rf = 0; rf < 2; ++rf)
#pragma unroll
    for (int fn = 0; fn < 8; ++fn) acc2[rf][fn] = z4;
#pragma unroll
  for (int ks = 0; ks < 4; ++ks) {
    short8 ah[2];
#pragma unroll
    for (int rf = 0; rf < 2; ++rf) {
      int rl = wbase + rf * 16 + c;
      int unit = ks * 4 + g;
      ah[rf] = *(const short8*)&Hbf[rl * 128 + ((unit ^ (rl & 15)) << 3)];
    }
#pragma unroll
    for (int fn = 0; fn < 8; ++fn) {
      size_t wb = (size_t)(fn * 16 + c) * 128 + ks * 32 + g * 8;
      short8 bh = *(const short8*)(W1h + wb);
      short8 bl = *(const short8*)(W1l + wb);
#pragma unroll
      for (int rf = 0; rf < 2; ++rf) {
        acc2[rf][fn] = __builtin_amdgcn_mfma_f32_16x16x32_bf16(ah[rf], bh, acc2[rf][fn], 0, 0, 0);
        acc2[rf][fn] = __builtin_amdgcn_mfma_f32_16x16x32_bf16(ah[rf], bl, acc2[rf][fn], 0, 0, 0);
      }
    }
  }

  // ---- epilogue, per row-fragment ----
  float colagg[8];
#pragma unroll
  for (int fn = 0; fn < 8; ++fn) colagg[fn] = 0.f;

#pragma unroll
  for (int rf = 0; rf < 2; ++rf) {
    const int rb = wbase + rf * 16 + g * 4;
    float sum[4] = {0.f, 0.f, 0.f, 0.f}, sq[4] = {0.f, 0.f, 0.f, 0.f};
    float xv[8][4];
#pragma unroll
    for (int fn = 0; fn < 8; ++fn) {
      int col = fn * 16 + c;
      float bb = b1[col];
#pragma unroll
      for (int ri = 0; ri < 4; ++ri) {
        int row = rb + ri;
        float e = fmaxf(acc2[rf][fn][ri] + bb, 0.f);
        if (row < valid) {
          if (EDGE_MODE) e_out[(size_t)(m0 + row) * L + col] = f2bf(e);
          colagg[fn] += e;
          float xprev;
          if (EDGE_MODE) xprev = xf[(size_t)(m0 + row) * L + col];
          else           xprev = unpackf(xp[(size_t)(m0 + row) * L + col]);
          float x = e + xprev;
          xv[fn][ri] = x;
          sum[ri] += x;
          sq[ri] += x * x;
        } else {
          xv[fn][ri] = 0.f;
        }
      }
    }
#pragma unroll
    for (int mask = 1; mask <= 8; mask <<= 1) {
#pragma unroll
      for (int ri = 0; ri < 4; ++ri) {
        sum[ri] += __shfl_xor(sum[ri], mask);
        sq[ri] += __shfl_xor(sq[ri], mask);
      }
    }
    float mu[4], rs[4];
#pragma unroll
    for (int ri = 0; ri < 4; ++ri) {
      mu[ri] = sum[ri] * (1.f / 128.f);
      float var = sq[ri] * (1.f / 128.f) - mu[ri] * mu[ri];
      rs[ri] = rsqrtf(var + 1e-6f);
    }
#pragma unroll
    for (int fn = 0; fn < 8; ++fn) {
      int col = fn * 16 + c;
      float lns = ln_s[col], lnb = ln_b[col];
#pragma unroll
      for (int ri = 0; ri < 4; ++ri) {
        int row = rb + ri;
        if (row < valid) {
          float y = (xv[fn][ri] - mu[ri]) * rs[ri] * lns + lnb;
          if (xf_out) xf_out[(size_t)(m0 + row) * L + col] = y;
          if (xp_out) xp_out[(size_t)(m0 + row) * L + col] = packf(y);
          if (xh_out) xh_out[(size_t)(m0 + row) * L + col] = f2bf(y);
        }
      }
    }
  }

  // column aggregate
#pragma unroll
  for (int mask = 16; mask <= 32; mask <<= 1)
#pragma unroll
    for (int fn = 0; fn < 8; ++fn) colagg[fn] += __shfl_xor(colagg[fn], mask);
  __syncthreads();               // all Hbf reads complete; reuse as float scratch
  float* F = (float*)SL;
  if (lane < 16) {
#pragma unroll
    for (int fn = 0; fn < 8; ++fn) F[wg * 128 + fn * 16 + lane] = colagg[fn];
  }
  __syncthreads();
  if (t < 128) {
    float s = 0.f;
#pragma unroll
    for (int w = 0; w < 4; ++w) s += F[w * 128 + t];
    atomicAdd(agg + t, s);
  }
}

// global update + LN + (optionally) next step's bias folds + agg reset
__global__ void glob_step_kernel(float* __restrict__ glob,
                                 float* __restrict__ node_agg, float* __restrict__ edge_agg,
                                 const float* __restrict__ W0, const float* __restrict__ b0,
                                 const float* __restrict__ W1, const float* __restrict__ b1,
                                 const float* __restrict__ ln_s, const float* __restrict__ ln_b,
                                 const float* __restrict__ eWg, const float* __restrict__ eb0,
                                 float* __restrict__ b0e,
                                 const float* __restrict__ nWg, const float* __restrict__ nb0,
                                 float* __restrict__ b0n) {
  __shared__ float gin[384];
  __shared__ float h[128];
  __shared__ float red4[4];
  __shared__ float gl[128];
  int j = threadIdx.x;  // 128
  gin[j] = node_agg[j];
  gin[128 + j] = edge_agg[j];
  gin[256 + j] = glob[j];
  __syncthreads();
  node_agg[j] = 0.f;
  edge_agg[j] = 0.f;
  float a = b0[j];
  for (int k = 0; k < 384; ++k) a += gin[k] * W0[k * L + j];
  h[j] = fmaxf(a, 0.f);
  __syncthreads();
  float o = b1[j];
  for (int k = 0; k < 128; ++k) o += h[k] * W1[k * L + j];
  o = fmaxf(o, 0.f);
  float x = o + gin[256 + j];
  float sum = x, sq = x * x;
  for (int m = 1; m < 64; m <<= 1) { sum += __shfl_xor(sum, m); sq += __shfl_xor(sq, m); }
  if ((j & 63) == 0) { red4[(j >> 6) * 2] = sum; red4[(j >> 6) * 2 + 1] = sq; }
  __syncthreads();
  sum = red4[0] + red4[2]; sq = red4[1] + red4[3];
  float mu = sum * (1.f / 128.f);
  float var = sq * (1.f / 128.f) - mu * mu;
  float rsd = rsqrtf(var + 1e-6f);
  float gnew = (x - mu) * rsd * ln_s[j] + ln_b[j];
  glob[j] = gnew;
  gl[j] = gnew;
  __syncthreads();
  if (eWg) {
    float ae = eb0[j], an = nb0[j];
    for (int k = 0; k < 128; ++k) {
      float g = gl[k];
      ae = fmaf(g, eWg[k * L + j], ae);
      an = fmaf(g, nWg[k * L + j], an);
    }
    b0e[j] = ae;
    b0n[j] = an;
  }
}

__global__ void decode_kernel(const float* __restrict__ glob, const float* __restrict__ W,
                              const float* __restrict__ bias, float* __restrict__ out) {
  int j = threadIdx.x;  // 128
  float a = bias[j];
  for (int k = 0; k < 128; ++k) a += glob[k] * W[k * L + j];
  out[j] = a;
}

extern "C" void kernel_launch(void* const* d_in, const int* in_sizes, int n_in,
                              void* d_out, int out_size, void* d_ws, size_t ws_size,
                              hipStream_t stream) {
  const float* node_feats = (const float*)d_in[0];
  const float* edge_feats = (const float*)d_in[1];
  const float* globals_   = (const float*)d_in[2];
  const int*   senders    = (const int*)d_in[3];
  const int*   receivers  = (const int*)d_in[4];
  const float* emb_node_W = (const float*)d_in[5];
  const float* emb_node_b = (const float*)d_in[6];
  const float* emb_edge_W = (const float*)d_in[7];
  const float* emb_edge_b = (const float*)d_in[8];
  const float* emb_glob_W = (const float*)d_in[9];
  const float* emb_glob_b = (const float*)d_in[10];
  const float* edge_W0 = (const float*)d_in[11];
  const float* edge_b0 = (const float*)d_in[12];
  const float* edge_W1 = (const float*)d_in[13];
  const float* edge_b1 = (const float*)d_in[14];
  const float* node_W0 = (const float*)d_in[15];
  const float* node_b0 = (const float*)d_in[16];
  const float* node_W1 = (const float*)d_in[17];
  const float* node_b1 = (const float*)d_in[18];
  const float* glob_W0 = (const float*)d_in[19];
  const float* glob_b0 = (const float*)d_in[20];
  const float* glob_W1 = (const float*)d_in[21];
  const float* glob_b1 = (const float*)d_in[22];
  const float* ln_node_s = (const float*)d_in[23];
  const float* ln_node_b = (const float*)d_in[24];
  const float* ln_edge_s = (const float*)d_in[25];
  const float* ln_edge_b = (const float*)d_in[26];
  const float* ln_glob_s = (const float*)d_in[27];
  const float* ln_glob_b = (const float*)d_in[28];
  const float* dec_W = (const float*)d_in[29];
  const float* dec_b = (const float*)d_in[30];

  const int N = in_sizes[0] / 64;
  const int E = in_sizes[1] / 32;

  float* nodes = (float*)d_out;                   // [N][128]
  float* edges = nodes + (size_t)N * L;           // [E][128] (live fp32 edge state)
  float* gout  = edges + (size_t)E * L;           // [128]

  char* wp = (char*)d_ws;
  auto alloc = [&](size_t bytes) -> char* {
    char* p = wp;
    wp += (bytes + 255) & ~(size_t)255;
    return p;
  };
  float* glob = (float*)alloc(512);
  float* node_agg = (float*)alloc(512);
  float* edge_agg = (float*)alloc(512);
  float* b0e_eff = (float*)alloc(512);
  float* b0n_eff = (float*)alloc(512);
  unsigned short* eW0c = (unsigned short*)alloc((size_t)NSTEPS * 12 * 8192 * 2);
  unsigned short* nW0c = (unsigned short*)alloc((size_t)NSTEPS * 12 * 8192 * 2);
  unsigned short* eW1h = (unsigned short*)alloc((size_t)NSTEPS * 128 * 128 * 2);
  unsigned short* eW1l = (unsigned short*)alloc((size_t)NSTEPS * 128 * 128 * 2);
  unsigned short* nW1h = (unsigned short*)alloc((size_t)NSTEPS * 128 * 128 * 2);
  unsigned short* nW1l = (unsigned short*)alloc((size_t)NSTEPS * 128 * 128 * 2);
  unsigned* nodes_p = (unsigned*)alloc((size_t)N * L * 4);
  unsigned short* nodes_h = (unsigned short*)alloc((size_t)N * L * 2);
  unsigned short* sent_h  = (unsigned short*)alloc((size_t)N * L * 2);
  unsigned short* recv_h  = (unsigned short*)alloc((size_t)N * L * 2);
  int* rp1 = (int*)alloc((size_t)(N + 1) * 4);
  int* rp2 = (int*)alloc((size_t)(N + 1) * 4);
  int* cnt1 = (int*)alloc((size_t)N * 4);
  int* cnt2 = (int*)alloc((size_t)N * 4);
  int* el1 = (int*)alloc((size_t)E * 4);
  int* el2 = (int*)alloc((size_t)E * 4);
  int* part = (int*)alloc(SCAN_B * 4);
  unsigned short* e16 = (unsigned short*)alloc((size_t)E * L * 2);
  (void)ws_size;

  // weight prep: layer0 fragment-ordered (conflict-free), layer1 transposed hi/lo
  conv_frag_kernel<<<(NSTEPS * 12 * 8192 + 255) / 256, 256, 0, stream>>>(edge_W0, eW0c, NSTEPS);
  conv_frag_kernel<<<(NSTEPS * 12 * 8192 + 255) / 256, 256, 0, stream>>>(node_W0, nW0c, NSTEPS);
  conv_split_kernel<<<(NSTEPS * 128 * 128 + 255) / 256, 256, 0, stream>>>(edge_W1, eW1h, eW1l, 128, 128, NSTEPS);
  conv_split_kernel<<<(NSTEPS * 128 * 128 + 255) / 256, 256, 0, stream>>>(node_W1, nW1h, nW1l, 128, 128, NSTEPS);

  // embeddings (exact fp32 math, W-in-register)
  embed_reg_kernel<64><<<2048, 128, 0, stream>>>(node_feats, emb_node_W, emb_node_b,
                                                 nullptr, nodes_p, nodes_h, N);
  embed_reg_kernel<32><<<4096, 128, 0, stream>>>(edge_feats, emb_edge_W, emb_edge_b,
                                                 edges, nullptr, nullptr, E);
  glob_embed_fold_kernel<<<1, 128, 0, stream>>>(globals_, emb_glob_W, emb_glob_b, glob,
                                                edge_W0 + 384 * L, edge_b0, b0e_eff,
                                                node_W0 + 384 * L, node_b0, b0n_eff,
                                                node_agg, edge_agg);

  // CSR build (once per launch)
  const int chunk = (N + SCAN_B - 1) / SCAN_B;
  hipMemsetAsync(cnt1, 0, (size_t)N * 4, stream);
  hipMemsetAsync(cnt2, 0, (size_t)N * 4, stream);
  hist_kernel<<<(E + 255) / 256, 256, 0, stream>>>(senders, receivers, cnt1, cnt2, E);
  scan_sum_kernel<<<SCAN_B, 256, 0, stream>>>(cnt1, part, N, chunk);
  scan_part_kernel<<<1, 64, 0, stream>>>(part, SCAN_B);
  scan_write_kernel<<<SCAN_B, 256, 0, stream>>>(cnt1, part, rp1, N, chunk, E);
  scan_sum_kernel<<<SCAN_B, 256, 0, stream>>>(cnt2, part, N, chunk);
  scan_part_kernel<<<1, 64, 0, stream>>>(part, SCAN_B);
  scan_write_kernel<<<SCAN_B, 256, 0, stream>>>(cnt2, part, rp2, N, chunk, E);
  hipMemsetAsync(cnt1, 0, (size_t)N * 4, stream);
  hipMemsetAsync(cnt2, 0, (size_t)N * 4, stream);
  fill_kernel<<<(E + 255) / 256, 256, 0, stream>>>(senders, receivers, rp1, rp2, cnt1, cnt2, el1, el2, E);

  const int egrid = (E + 127) / 128;
  const int ngrid = (N + 127) / 128;

  for (int s = 0; s < NSTEPS; ++s) {
    const bool last = (s == NSTEPS - 1);

    block_step_kernel<true><<<egrid, 256, 0, stream>>>(
        edges, nullptr, nodes_h, nodes_h, senders, receivers,
        eW0c + (size_t)s * 12 * 8192, b0e_eff,
        eW1h + (size_t)s * 128 * 128, eW1l + (size_t)s * 128 * 128, edge_b1 + s * L,
        ln_edge_s + s * L, ln_edge_b + s * L,
        edge_agg, e16, edges, nullptr, nullptr, E);

    gather_kernel<<<(N + 15) / 16, 256, 0, stream>>>(e16, rp1, el1, rp2, el2, sent_h, recv_h, N);

    block_step_kernel<false><<<ngrid, 256, 0, stream>>>(
        nullptr, nodes_p, sent_h, recv_h, nullptr, nullptr,
        nW0c + (size_t)s * 12 * 8192, b0n_eff,
        nW1h + (size_t)s * 128 * 128, nW1l + (size_t)s * 128 * 128, node_b1 + s * L,
        ln_node_s + s * L, ln_node_b + s * L,
        node_agg, nullptr, last ? nodes : nullptr, last ? nullptr : nodes_p,
        last ? nullptr : nodes_h, N);

    glob_step_kernel<<<1, 128, 0, stream>>>(
        glob, node_agg, edge_agg,
        glob_W0 + (size_t)s * 384 * L, glob_b0 + s * L,
        glob_W1 + (size_t)s * 128 * L, glob_b1 + s * L,
        ln_glob_s + s * L, ln_glob_b + s * L,
        last ? nullptr : (edge_W0 + (size_t)1 * 512 * L + 384 * L),
        last ? nullptr : (edge_b0 + 1 * L), b0e_eff,
        last ? nullptr : (node_W0 + (size_t)1 * 512 * L + 384 * L),
        last ? nullptr : (node_b0 + 1 * L), b0n_eff);
  }

  decode_kernel<<<1, 128, 0, stream>>>(glob, dec_W, dec_b, gout);
}